// Round 1
// baseline (633.372 us; speedup 1.0000x reference)
//
#include <hip/hip_runtime.h>
#include <cmath>

namespace {

constexpr int D = 256;     // feature dim (fixed by reference)
constexpr int BM = 128;    // rows (f) per block tile
constexpr int BN = 64;     // cols (a) per block tile
constexpr int KB = 16;     // K-chunk staged in LDS
constexpr int PAD = 20;    // LDS row stride in floats (16 data + 4 pad, 16B aligned)

// --- row L2 normalize: one wave per row, float4 per lane (64*4 = 256) ---
__global__ __launch_bounds__(256) void normalize_rows(const float* __restrict__ in,
                                                      float* __restrict__ out) {
  const int wave = threadIdx.x >> 6;
  const int lane = threadIdx.x & 63;
  const size_t row = (size_t)blockIdx.x * 4 + wave;
  const float4 v = reinterpret_cast<const float4*>(in + row * D)[lane];
  float ss = v.x * v.x + v.y * v.y + v.z * v.z + v.w * v.w;
#pragma unroll
  for (int m = 32; m >= 1; m >>= 1) ss += __shfl_xor(ss, m, 64);
  const float scale = 1.0f / fmaxf(sqrtf(ss), 1e-12f);
  float4 o;
  o.x = v.x * scale; o.y = v.y * scale; o.z = v.z * scale; o.w = v.w * scale;
  reinterpret_cast<float4*>(out + row * D)[lane] = o;
}

__device__ __forceinline__ float logit_from_sim(float s) {
  const float d2 = fmaxf(2.0f - 2.0f * s, 0.0f);
  const float dist = sqrtf(d2);
  return fmaxf(1.0f / (dist + 1e-8f), 1e-8f);
}

// --- main stage: BM x BN logit tile, reduce to per-row (max, sumexp) partials ---
__global__ __launch_bounds__(256) void tile_partial_lse(
    const float* __restrict__ fn, const float* __restrict__ an,
    float2* __restrict__ partials, int N) {
  __shared__ float Fs[BM * PAD];
  __shared__ float As[BN * PAD];
  const int tid = threadIdx.x;
  const int tx = tid & 15;   // 16 col-groups * 4 cols = 64
  const int ty = tid >> 4;   // 16 row-groups * 8 rows = 128
  const int brow = blockIdx.x;
  const int bcol = blockIdx.y;
  const int ncb = gridDim.y;

  const float* fbase = fn + (size_t)brow * BM * D;
  const float* abase = an + (size_t)bcol * BN * D;

  float acc[8][4];
#pragma unroll
  for (int r = 0; r < 8; ++r)
#pragma unroll
    for (int c = 0; c < 4; ++c) acc[r][c] = 0.0f;

  for (int k0 = 0; k0 < D; k0 += KB) {
    __syncthreads();
    // stage F tile: BM rows x KB floats = 512 float4 (2 per thread)
#pragma unroll
    for (int t = tid; t < BM * 4; t += 256) {
      const int row = t >> 2, kq = t & 3;
      const float4 v = *reinterpret_cast<const float4*>(fbase + row * D + k0 + kq * 4);
      *reinterpret_cast<float4*>(&Fs[row * PAD + kq * 4]) = v;
    }
    // stage A tile: BN rows x KB floats = 256 float4 (1 per thread)
#pragma unroll
    for (int t = tid; t < BN * 4; t += 256) {
      const int row = t >> 2, kq = t & 3;
      const float4 v = *reinterpret_cast<const float4*>(abase + row * D + k0 + kq * 4);
      *reinterpret_cast<float4*>(&As[row * PAD + kq * 4]) = v;
    }
    __syncthreads();
#pragma unroll
    for (int kq = 0; kq < 4; ++kq) {
      float4 a4[4], f4[8];
#pragma unroll
      for (int c = 0; c < 4; ++c)
        a4[c] = *reinterpret_cast<const float4*>(&As[(tx * 4 + c) * PAD + kq * 4]);
#pragma unroll
      for (int r = 0; r < 8; ++r)
        f4[r] = *reinterpret_cast<const float4*>(&Fs[(ty * 8 + r) * PAD + kq * 4]);
#pragma unroll
      for (int r = 0; r < 8; ++r)
#pragma unroll
        for (int c = 0; c < 4; ++c) {
          acc[r][c] += f4[r].x * a4[c].x;
          acc[r][c] += f4[r].y * a4[c].y;
          acc[r][c] += f4[r].z * a4[c].z;
          acc[r][c] += f4[r].w * a4[c].w;
        }
    }
  }

  // logits + per-row (max, sum of exp) over this BN-column block.
  // Row r of a row-group is held by the 16 consecutive lanes with the same ty.
#pragma unroll
  for (int r = 0; r < 8; ++r) {
    float lv[4];
#pragma unroll
    for (int c = 0; c < 4; ++c) lv[c] = logit_from_sim(acc[r][c]);
    float m = fmaxf(fmaxf(lv[0], lv[1]), fmaxf(lv[2], lv[3]));
#pragma unroll
    for (int msk = 1; msk <= 8; msk <<= 1) m = fmaxf(m, __shfl_xor(m, msk, 64));
    float s = 0.0f;
#pragma unroll
    for (int c = 0; c < 4; ++c) s += expf(lv[c] - m);
#pragma unroll
    for (int msk = 1; msk <= 8; msk <<= 1) s += __shfl_xor(s, msk, 64);
    if (tx == 0) {
      const int row = brow * BM + ty * 8 + r;
      partials[(size_t)row * ncb + bcol] = make_float2(m, s);
    }
  }
}

// --- combine per-row partials into LSE, subtract diagonal logit ---
__global__ __launch_bounds__(256) void combine_rows(
    const float2* __restrict__ partials, const float* __restrict__ fn,
    const float* __restrict__ an, float* __restrict__ terms, int N, int ncb) {
  const int i = blockIdx.x * blockDim.x + threadIdx.x;
  if (i >= N) return;
  float M = -INFINITY;
  for (int cb = 0; cb < ncb; ++cb) M = fmaxf(M, partials[(size_t)i * ncb + cb].x);
  float S = 0.0f;
  for (int cb = 0; cb < ncb; ++cb) {
    const float2 p = partials[(size_t)i * ncb + cb];
    S += p.y * expf(p.x - M);
  }
  // diagonal logit: dot(f_i, a_i)
  const float4* fp = reinterpret_cast<const float4*>(fn + (size_t)i * D);
  const float4* ap = reinterpret_cast<const float4*>(an + (size_t)i * D);
  float dot = 0.0f;
#pragma unroll 8
  for (int q = 0; q < D / 4; ++q) {
    const float4 f = fp[q], a = ap[q];
    dot += f.x * a.x + f.y * a.y + f.z * a.z + f.w * a.w;
  }
  const float lii = logit_from_sim(dot);
  terms[i] = (M + logf(S)) - lii;
}

// --- deterministic final reduction: one block ---
__global__ __launch_bounds__(256) void reduce_terms(const float* __restrict__ terms,
                                                    float* __restrict__ out, int N) {
  __shared__ float red[4];
  float s = 0.0f;
  for (int i = threadIdx.x; i < N; i += 256) s += terms[i];
#pragma unroll
  for (int m = 32; m >= 1; m >>= 1) s += __shfl_xor(s, m, 64);
  const int wave = threadIdx.x >> 6;
  if ((threadIdx.x & 63) == 0) red[wave] = s;
  __syncthreads();
  if (threadIdx.x == 0) {
    out[0] = (red[0] + red[1] + red[2] + red[3]) / (float)N;
  }
}

}  // namespace

extern "C" void kernel_launch(void* const* d_in, const int* in_sizes, int n_in,
                              void* d_out, int out_size, void* d_ws, size_t ws_size,
                              hipStream_t stream) {
  const float* face = (const float*)d_in[0];
  const float* audio = (const float*)d_in[1];
  const int N = in_sizes[0] / D;  // 8192

  // workspace layout (floats): fn[N*D] | an[N*D] | partials[N*ncb]*2 | terms[N]
  float* fn = (float*)d_ws;
  float* an = fn + (size_t)N * D;
  float2* partials = (float2*)(an + (size_t)N * D);
  const int ncb = N / BN;
  float* terms = (float*)(partials + (size_t)N * ncb);

  normalize_rows<<<N / 4, 256, 0, stream>>>(face, fn);
  normalize_rows<<<N / 4, 256, 0, stream>>>(audio, an);
  dim3 grid(N / BM, N / BN);
  tile_partial_lse<<<grid, 256, 0, stream>>>(fn, an, partials, N);
  combine_rows<<<(N + 255) / 256, 256, 0, stream>>>(partials, fn, an, terms, N, ncb);
  reduce_terms<<<1, 256, 0, stream>>>(terms, (float*)d_out, N);
}

// Round 2
// 240.255 us; speedup vs baseline: 2.6363x; 2.6363x over previous
//
#include <hip/hip_runtime.h>
#include <hip/hip_bf16.h>
#include <cmath>

namespace {

constexpr int D = 256;     // feature dim (fixed by reference)
constexpr int BM = 128;    // rows (f) per block tile
constexpr int BN = 128;    // cols (a) per block tile
constexpr int BK = 64;     // K-chunk staged in LDS
constexpr int LDK = BK + 8;  // LDS row stride in bf16 (144 B) -> even bank spread

typedef __attribute__((ext_vector_type(8))) short bf16x8;
typedef __attribute__((ext_vector_type(4))) float f32x4;

__device__ __forceinline__ unsigned short f2bf(float x) {
  unsigned int u = __float_as_uint(x);
  u += 0x7FFFu + ((u >> 16) & 1u);  // round-to-nearest-even
  return (unsigned short)(u >> 16);
}
__device__ __forceinline__ float bf2f(unsigned short b) {
  return __uint_as_float(((unsigned int)b) << 16);
}

__device__ __forceinline__ float logit_from_sim(float s) {
  const float d2 = fmaxf(2.0f - 2.0f * s, 0.0f);
  const float dist = sqrtf(d2);
  return fmaxf(1.0f / (dist + 1e-8f), 1e-8f);
}

// --- row L2 normalize fp32 -> bf16: one wave per row ---
__global__ __launch_bounds__(256) void normalize_rows_bf(
    const float* __restrict__ in, unsigned short* __restrict__ out) {
  const int wave = threadIdx.x >> 6;
  const int lane = threadIdx.x & 63;
  const size_t row = (size_t)blockIdx.x * 4 + wave;
  const float4 v = reinterpret_cast<const float4*>(in + row * D)[lane];
  float ss = v.x * v.x + v.y * v.y + v.z * v.z + v.w * v.w;
#pragma unroll
  for (int m = 32; m >= 1; m >>= 1) ss += __shfl_xor(ss, m, 64);
  const float scale = 1.0f / fmaxf(sqrtf(ss), 1e-12f);
  ushort4 o;
  o.x = f2bf(v.x * scale);
  o.y = f2bf(v.y * scale);
  o.z = f2bf(v.z * scale);
  o.w = f2bf(v.w * scale);
  reinterpret_cast<ushort4*>(out + row * D)[lane] = o;
}

// --- main stage: 128x128 sim tile via bf16 MFMA, reduce to per-row (max, sumexp) ---
__global__ __launch_bounds__(256) void tile_partial_lse(
    const unsigned short* __restrict__ fnb, const unsigned short* __restrict__ anb,
    float2* __restrict__ partials, int N, int ncb) {
  __shared__ short Fs[BM * LDK];  // 18 KB
  __shared__ short As[BN * LDK];  // 18 KB
  const int tid = threadIdx.x;
  const int wv = tid >> 6;          // wave 0..3 -> rows wv*32..wv*32+31
  const int lane = tid & 63;
  const int l15 = lane & 15;
  const int half = lane >> 4;       // 0..3
  const int brow = blockIdx.x;
  const int bcol = blockIdx.y;

  const unsigned short* fbase = fnb + (size_t)brow * BM * D;
  const unsigned short* abase = anb + (size_t)bcol * BN * D;

  f32x4 acc[2][8];
#pragma unroll
  for (int m = 0; m < 2; ++m)
#pragma unroll
    for (int n = 0; n < 8; ++n) acc[m][n] = (f32x4){0.f, 0.f, 0.f, 0.f};

  // staging indices: idx in [0,1024): row = idx>>3, chunk(8 bf16) = idx&7
  for (int kt = 0; kt < D / BK; ++kt) {
    const int k0 = kt * BK;
    uint4 fr[4], ar[4];
#pragma unroll
    for (int q = 0; q < 4; ++q) {
      const int idx = q * 256 + tid;
      const int row = idx >> 3, chunk = idx & 7;
      fr[q] = *reinterpret_cast<const uint4*>(fbase + (size_t)row * D + k0 + chunk * 8);
      ar[q] = *reinterpret_cast<const uint4*>(abase + (size_t)row * D + k0 + chunk * 8);
    }
    if (kt > 0) __syncthreads();  // prev compute done before overwrite
#pragma unroll
    for (int q = 0; q < 4; ++q) {
      const int idx = q * 256 + tid;
      const int row = idx >> 3, chunk = idx & 7;
      *reinterpret_cast<uint4*>(&Fs[row * LDK + chunk * 8]) = fr[q];
      *reinterpret_cast<uint4*>(&As[row * LDK + chunk * 8]) = ar[q];
    }
    __syncthreads();
#pragma unroll
    for (int h = 0; h < 2; ++h) {  // two K=32 halves of BK=64
      bf16x8 afr[2], bfr[8];
#pragma unroll
      for (int m = 0; m < 2; ++m)
        afr[m] = *reinterpret_cast<const bf16x8*>(
            &Fs[(wv * 32 + m * 16 + l15) * LDK + h * 32 + half * 8]);
#pragma unroll
      for (int n = 0; n < 8; ++n)
        bfr[n] = *reinterpret_cast<const bf16x8*>(
            &As[(n * 16 + l15) * LDK + h * 32 + half * 8]);
#pragma unroll
      for (int m = 0; m < 2; ++m)
#pragma unroll
        for (int n = 0; n < 8; ++n)
          acc[m][n] = __builtin_amdgcn_mfma_f32_16x16x32_bf16(afr[m], bfr[n],
                                                              acc[m][n], 0, 0, 0);
    }
  }

  // Epilogue: logits + per-row (max, sumexp) over the 128 cols of this tile.
  // C/D layout: col = bcol*128 + n*16 + l15, row = wv*32 + m*16 + half*4 + e.
#pragma unroll
  for (int m = 0; m < 2; ++m) {
#pragma unroll
    for (int e = 0; e < 4; ++e) {
      float lv[8];
      float mx = -INFINITY;
#pragma unroll
      for (int n = 0; n < 8; ++n) {
        lv[n] = logit_from_sim(acc[m][n][e]);
        mx = fmaxf(mx, lv[n]);
      }
#pragma unroll
      for (int msk = 1; msk <= 8; msk <<= 1) mx = fmaxf(mx, __shfl_xor(mx, msk, 64));
      float s = 0.0f;
#pragma unroll
      for (int n = 0; n < 8; ++n) s += __expf(lv[n] - mx);
#pragma unroll
      for (int msk = 1; msk <= 8; msk <<= 1) s += __shfl_xor(s, msk, 64);
      if (l15 == 0) {
        const int row = brow * BM + wv * 32 + m * 16 + half * 4 + e;
        partials[(size_t)row * ncb + bcol] = make_float2(mx, s);
      }
    }
  }
}

// --- combine per-row partials into LSE, subtract diagonal logit ---
__global__ __launch_bounds__(256) void combine_rows(
    const float2* __restrict__ partials, const unsigned short* __restrict__ fnb,
    const unsigned short* __restrict__ anb, float* __restrict__ terms, int N, int ncb) {
  const int i = blockIdx.x * blockDim.x + threadIdx.x;
  if (i >= N) return;
  float M = -INFINITY;
  for (int cb = 0; cb < ncb; ++cb) M = fmaxf(M, partials[(size_t)i * ncb + cb].x);
  float S = 0.0f;
  for (int cb = 0; cb < ncb; ++cb) {
    const float2 p = partials[(size_t)i * ncb + cb];
    S += p.y * __expf(p.x - M);
  }
  // diagonal logit: dot(f_i, a_i) from the same bf16 data the MFMA consumed
  const uint4* fp = reinterpret_cast<const uint4*>(fnb + (size_t)i * D);
  const uint4* ap = reinterpret_cast<const uint4*>(anb + (size_t)i * D);
  float dot = 0.0f;
#pragma unroll 4
  for (int q = 0; q < D / 8; ++q) {
    const uint4 f = fp[q], a = ap[q];
    const unsigned int fw[4] = {f.x, f.y, f.z, f.w};
    const unsigned int aw[4] = {a.x, a.y, a.z, a.w};
#pragma unroll
    for (int w = 0; w < 4; ++w) {
      dot += __uint_as_float(fw[w] << 16) * __uint_as_float(aw[w] << 16);
      dot += __uint_as_float(fw[w] & 0xFFFF0000u) * __uint_as_float(aw[w] & 0xFFFF0000u);
    }
  }
  const float lii = logit_from_sim(dot);
  terms[i] = (M + logf(S)) - lii;
}

// --- deterministic final reduction: one block ---
__global__ __launch_bounds__(256) void reduce_terms(const float* __restrict__ terms,
                                                    float* __restrict__ out, int N) {
  __shared__ float red[4];
  float s = 0.0f;
  for (int i = threadIdx.x; i < N; i += 256) s += terms[i];
#pragma unroll
  for (int m = 32; m >= 1; m >>= 1) s += __shfl_xor(s, m, 64);
  const int wave = threadIdx.x >> 6;
  if ((threadIdx.x & 63) == 0) red[wave] = s;
  __syncthreads();
  if (threadIdx.x == 0) {
    out[0] = (red[0] + red[1] + red[2] + red[3]) / (float)N;
  }
}

}  // namespace

extern "C" void kernel_launch(void* const* d_in, const int* in_sizes, int n_in,
                              void* d_out, int out_size, void* d_ws, size_t ws_size,
                              hipStream_t stream) {
  const float* face = (const float*)d_in[0];
  const float* audio = (const float*)d_in[1];
  const int N = in_sizes[0] / D;  // 8192
  const int ncb = N / BN;         // 64

  // workspace layout: fnb[N*D] bf16 | anb[N*D] bf16 | partials[N*ncb] float2 | terms[N] f32
  unsigned short* fnb = (unsigned short*)d_ws;
  unsigned short* anb = fnb + (size_t)N * D;
  float2* partials = (float2*)(anb + (size_t)N * D);
  float* terms = (float*)(partials + (size_t)N * ncb);

  normalize_rows_bf<<<N / 4, 256, 0, stream>>>(face, fnb);
  normalize_rows_bf<<<N / 4, 256, 0, stream>>>(audio, anb);
  dim3 grid(N / BM, N / BN);
  tile_partial_lse<<<grid, 256, 0, stream>>>(fnb, anb, partials, N, ncb);
  combine_rows<<<(N + 255) / 256, 256, 0, stream>>>(partials, fnb, anb, terms, N, ncb);
  reduce_terms<<<1, 256, 0, stream>>>(terms, (float*)d_out, N);
}

// Round 3
// 139.669 us; speedup vs baseline: 4.5348x; 1.7202x over previous
//
#include <hip/hip_runtime.h>
#include <hip/hip_bf16.h>
#include <cmath>

namespace {

constexpr int D = 256;   // feature dim (fixed by reference)
constexpr int BM = 128;  // rows (f) per block tile
constexpr int BN = 128;  // cols (a) per block tile
constexpr int BK = 64;   // K-chunk staged in LDS (128 B/row = 8 x 16B chunks)

typedef __attribute__((ext_vector_type(8))) short bf16x8;
typedef __attribute__((ext_vector_type(4))) float f32x4;

__device__ __forceinline__ unsigned short f2bf(float x) {
  unsigned int u = __float_as_uint(x);
  u += 0x7FFFu + ((u >> 16) & 1u);  // round-to-nearest-even
  return (unsigned short)(u >> 16);
}

__device__ __forceinline__ float logit_from_sim(float s) {
  const float d2 = fmaxf(2.0f - 2.0f * s, 0.0f);
  const float dist = sqrtf(d2);
  return fmaxf(1.0f / (dist + 1e-8f), 1e-8f);
}

__device__ __forceinline__ void gload_lds16(const unsigned short* g, short* l) {
  __builtin_amdgcn_global_load_lds(
      (const __attribute__((address_space(1))) void*)g,
      (__attribute__((address_space(3))) void*)l, 16, 0, 0);
}

// --- row L2 normalize fp32 -> bf16: one wave per row ---
__global__ __launch_bounds__(256) void normalize_rows_bf(
    const float* __restrict__ in, unsigned short* __restrict__ out) {
  const int wave = threadIdx.x >> 6;
  const int lane = threadIdx.x & 63;
  const size_t row = (size_t)blockIdx.x * 4 + wave;
  const float4 v = reinterpret_cast<const float4*>(in + row * D)[lane];
  float ss = v.x * v.x + v.y * v.y + v.z * v.z + v.w * v.w;
#pragma unroll
  for (int m = 32; m >= 1; m >>= 1) ss += __shfl_xor(ss, m, 64);
  const float scale = 1.0f / fmaxf(sqrtf(ss), 1e-12f);
  ushort4 o;
  o.x = f2bf(v.x * scale);
  o.y = f2bf(v.y * scale);
  o.z = f2bf(v.z * scale);
  o.w = f2bf(v.w * scale);
  reinterpret_cast<ushort4*>(out + row * D)[lane] = o;
}

// --- main stage: 128x128 sim tile via bf16 MFMA, reduce to per-row (max, sumexp) ---
// Staging: global_load_lds width=16, linear LDS dest, XOR-swizzled SOURCE chunks
// (j' = j ^ (row&7) in 16B units); ds_read applies the same XOR -> conflict-free.
__global__ __launch_bounds__(256, 3) void tile_partial_lse(
    const unsigned short* __restrict__ fnb, const unsigned short* __restrict__ anb,
    float2* __restrict__ partials, int N, int ncb) {
  __shared__ short Fs[BM * BK];  // 16 KB
  __shared__ short As[BN * BK];  // 16 KB
  const int tid = threadIdx.x;
  const int wv = tid >> 6;    // wave 0..3 -> rows wv*32..wv*32+31
  const int lane = tid & 63;
  const int l15 = lane & 15;
  const int half = lane >> 4;  // 0..3
  const int brow = blockIdx.x;
  const int bcol = blockIdx.y;

  const unsigned short* fbase = fnb + (size_t)brow * BM * D;
  const unsigned short* abase = anb + (size_t)bcol * BN * D;

  f32x4 acc[2][8];
#pragma unroll
  for (int m = 0; m < 2; ++m)
#pragma unroll
    for (int n = 0; n < 8; ++n) acc[m][n] = (f32x4){0.f, 0.f, 0.f, 0.f};

  for (int kt = 0; kt < D / BK; ++kt) {
    if (kt > 0) __syncthreads();  // prev compute done before overwrite
    // stage: 1024 chunks of 16B per matrix; chunk c -> row r=c>>3, slot j=c&7.
    // LDS dest is linear (base + lane*16); source chunk is j ^ (r&7).
#pragma unroll
    for (int q = 0; q < 4; ++q) {
      const int c = q * 256 + tid;
      const int r = c >> 3;
      const int js = (c & 7) ^ (r & 7);
      const unsigned short* gf = fbase + r * D + kt * BK + js * 8;
      const unsigned short* ga = abase + r * D + kt * BK + js * 8;
      gload_lds16(gf, &Fs[c * 8]);
      gload_lds16(ga, &As[c * 8]);
    }
    __syncthreads();  // vmcnt drained by compiler before barrier
#pragma unroll
    for (int h = 0; h < 2; ++h) {  // two K=32 halves of BK=64
      bf16x8 afr[2], bfr[8];
      const int j = h * 4 + half;  // 16B slot within the 8-slot row
#pragma unroll
      for (int m = 0; m < 2; ++m) {
        const int row = wv * 32 + m * 16 + l15;
        afr[m] = *reinterpret_cast<const bf16x8*>(&Fs[(row * 8 + (j ^ (row & 7))) * 8]);
      }
#pragma unroll
      for (int n = 0; n < 8; ++n) {
        const int row = n * 16 + l15;
        bfr[n] = *reinterpret_cast<const bf16x8*>(&As[(row * 8 + (j ^ (row & 7))) * 8]);
      }
#pragma unroll
      for (int m = 0; m < 2; ++m)
#pragma unroll
        for (int n = 0; n < 8; ++n)
          acc[m][n] = __builtin_amdgcn_mfma_f32_16x16x32_bf16(afr[m], bfr[n],
                                                              acc[m][n], 0, 0, 0);
    }
  }

  // Epilogue: logits + per-row (max, sumexp) over the 128 cols of this tile.
  // C/D layout: col = bcol*128 + n*16 + l15, row = wv*32 + m*16 + half*4 + e.
#pragma unroll
  for (int m = 0; m < 2; ++m) {
#pragma unroll
    for (int e = 0; e < 4; ++e) {
      float lv[8];
      float mx = -INFINITY;
#pragma unroll
      for (int n = 0; n < 8; ++n) {
        lv[n] = logit_from_sim(acc[m][n][e]);
        mx = fmaxf(mx, lv[n]);
      }
#pragma unroll
      for (int msk = 1; msk <= 8; msk <<= 1) mx = fmaxf(mx, __shfl_xor(mx, msk, 64));
      float s = 0.0f;
#pragma unroll
      for (int n = 0; n < 8; ++n) s += __expf(lv[n] - mx);
#pragma unroll
      for (int msk = 1; msk <= 8; msk <<= 1) s += __shfl_xor(s, msk, 64);
      if (l15 == 0) {
        const int row = brow * BM + wv * 32 + m * 16 + half * 4 + e;
        partials[(size_t)row * ncb + bcol] = make_float2(mx, s);
      }
    }
  }
}

// --- combine per-row partials into LSE, subtract diagonal logit ---
__global__ __launch_bounds__(256) void combine_rows(
    const float2* __restrict__ partials, const unsigned short* __restrict__ fnb,
    const unsigned short* __restrict__ anb, float* __restrict__ terms, int N, int ncb) {
  const int i = blockIdx.x * blockDim.x + threadIdx.x;
  if (i >= N) return;
  float M = -INFINITY;
  for (int cb = 0; cb < ncb; ++cb) M = fmaxf(M, partials[(size_t)i * ncb + cb].x);
  float S = 0.0f;
  for (int cb = 0; cb < ncb; ++cb) {
    const float2 p = partials[(size_t)i * ncb + cb];
    S += p.y * __expf(p.x - M);
  }
  // diagonal logit: dot(f_i, a_i) from the same bf16 data the MFMA consumed
  const uint4* fp = reinterpret_cast<const uint4*>(fnb + (size_t)i * D);
  const uint4* ap = reinterpret_cast<const uint4*>(anb + (size_t)i * D);
  float dot = 0.0f;
#pragma unroll 4
  for (int q = 0; q < D / 8; ++q) {
    const uint4 f = fp[q], a = ap[q];
    const unsigned int fw[4] = {f.x, f.y, f.z, f.w};
    const unsigned int aw[4] = {a.x, a.y, a.z, a.w};
#pragma unroll
    for (int w = 0; w < 4; ++w) {
      dot += __uint_as_float(fw[w] << 16) * __uint_as_float(aw[w] << 16);
      dot += __uint_as_float(fw[w] & 0xFFFF0000u) * __uint_as_float(aw[w] & 0xFFFF0000u);
    }
  }
  const float lii = logit_from_sim(dot);
  terms[i] = (M + logf(S)) - lii;
}

// --- deterministic final reduction: one block ---
__global__ __launch_bounds__(256) void reduce_terms(const float* __restrict__ terms,
                                                    float* __restrict__ out, int N) {
  __shared__ float red[4];
  float s = 0.0f;
  for (int i = threadIdx.x; i < N; i += 256) s += terms[i];
#pragma unroll
  for (int m = 32; m >= 1; m >>= 1) s += __shfl_xor(s, m, 64);
  const int wave = threadIdx.x >> 6;
  if ((threadIdx.x & 63) == 0) red[wave] = s;
  __syncthreads();
  if (threadIdx.x == 0) {
    out[0] = (red[0] + red[1] + red[2] + red[3]) / (float)N;
  }
}

}  // namespace

extern "C" void kernel_launch(void* const* d_in, const int* in_sizes, int n_in,
                              void* d_out, int out_size, void* d_ws, size_t ws_size,
                              hipStream_t stream) {
  const float* face = (const float*)d_in[0];
  const float* audio = (const float*)d_in[1];
  const int N = in_sizes[0] / D;  // 8192
  const int ncb = N / BN;         // 64

  // workspace layout: fnb[N*D] bf16 | anb[N*D] bf16 | partials[N*ncb] float2 | terms[N] f32
  unsigned short* fnb = (unsigned short*)d_ws;
  unsigned short* anb = fnb + (size_t)N * D;
  float2* partials = (float2*)(anb + (size_t)N * D);
  float* terms = (float*)(partials + (size_t)N * ncb);

  normalize_rows_bf<<<N / 4, 256, 0, stream>>>(face, fnb);
  normalize_rows_bf<<<N / 4, 256, 0, stream>>>(audio, anb);
  dim3 grid(N / BM, N / BN);
  tile_partial_lse<<<grid, 256, 0, stream>>>(fnb, anb, partials, N, ncb);
  combine_rows<<<(N + 255) / 256, 256, 0, stream>>>(partials, fnb, anb, terms, N, ncb);
  reduce_terms<<<1, 256, 0, stream>>>(terms, (float*)d_out, N);
}

// Round 4
// 77.355 us; speedup vs baseline: 8.1879x; 1.8056x over previous
//
#include <hip/hip_runtime.h>
#include <hip/hip_bf16.h>
#include <cmath>

namespace {

constexpr int D = 256;   // feature dim (fixed by reference)
constexpr int BM = 128;  // rows (f) per block tile
constexpr int BN = 128;  // cols (a) per block tile
constexpr int BK = 64;   // K-chunk staged in LDS (128 B/row = 8 x 16B chunks)

typedef __attribute__((ext_vector_type(8))) short bf16x8;
typedef __attribute__((ext_vector_type(4))) float f32x4;

__device__ __forceinline__ unsigned short f2bf(float x) {
  unsigned int u = __float_as_uint(x);
  u += 0x7FFFu + ((u >> 16) & 1u);  // round-to-nearest-even
  return (unsigned short)(u >> 16);
}

// logit = 1/(sqrt(max(2-2s,0))+1e-8), approximated with v_rsq_f32.
// For unit-norm rows dist<=2 so logit>=0.5; eps shifts by ~5e-9 (negligible
// vs 0.18 threshold). Guard d2>0 and cap at 80 so exp stays finite even in
// a degenerate near-duplicate case.
__device__ __forceinline__ float fast_logit(float s) {
  const float d2 = fmaxf(fmaf(-2.0f, s, 2.0f), 1e-20f);
  return fminf(__builtin_amdgcn_rsqf(d2), 80.0f);
}

__device__ __forceinline__ void gload_lds16(const unsigned short* g, short* l) {
  __builtin_amdgcn_global_load_lds(
      (const __attribute__((address_space(1))) void*)g,
      (__attribute__((address_space(3))) void*)l, 16, 0, 0);
}

// --- row L2 normalize fp32 -> bf16: one wave per row ---
__global__ __launch_bounds__(256) void normalize_rows_bf(
    const float* __restrict__ in, unsigned short* __restrict__ out) {
  const int wave = threadIdx.x >> 6;
  const int lane = threadIdx.x & 63;
  const size_t row = (size_t)blockIdx.x * 4 + wave;
  const float4 v = reinterpret_cast<const float4*>(in + row * D)[lane];
  float ss = v.x * v.x + v.y * v.y + v.z * v.z + v.w * v.w;
#pragma unroll
  for (int m = 32; m >= 1; m >>= 1) ss += __shfl_xor(ss, m, 64);
  const float scale = __builtin_amdgcn_rsqf(fmaxf(ss, 1e-24f));
  ushort4 o;
  o.x = f2bf(v.x * scale);
  o.y = f2bf(v.y * scale);
  o.z = f2bf(v.z * scale);
  o.w = f2bf(v.w * scale);
  reinterpret_cast<ushort4*>(out + row * D)[lane] = o;
}

// --- main stage: 128x128 sim tile via bf16 MFMA -> per-row sum(exp(logit)) ---
// Staging: global_load_lds width=16, linear LDS dest, XOR-swizzled SOURCE chunks
// (j' = j ^ (row&7) in 16B units); ds_read applies the same XOR -> conflict-free.
__global__ __launch_bounds__(256, 3) void tile_partial_lse(
    const unsigned short* __restrict__ fnb, const unsigned short* __restrict__ anb,
    float* __restrict__ partials, int N, int ncb) {
  __shared__ short Fs[BM * BK];  // 16 KB
  __shared__ short As[BN * BK];  // 16 KB
  const int tid = threadIdx.x;
  const int wv = tid >> 6;    // wave 0..3 -> rows wv*32..wv*32+31
  const int lane = tid & 63;
  const int l15 = lane & 15;
  const int half = lane >> 4;  // 0..3
  const int brow = blockIdx.x;
  const int bcol = blockIdx.y;

  const unsigned short* fbase = fnb + (size_t)brow * BM * D;
  const unsigned short* abase = anb + (size_t)bcol * BN * D;

  f32x4 acc[2][8];
#pragma unroll
  for (int m = 0; m < 2; ++m)
#pragma unroll
    for (int n = 0; n < 8; ++n) acc[m][n] = (f32x4){0.f, 0.f, 0.f, 0.f};

  for (int kt = 0; kt < D / BK; ++kt) {
    if (kt > 0) __syncthreads();  // prev compute done before overwrite
    // stage: 1024 chunks of 16B per matrix; chunk c -> row r=c>>3, slot j=c&7.
    // LDS dest is linear (base + lane*16); source chunk is j ^ (r&7).
#pragma unroll
    for (int q = 0; q < 4; ++q) {
      const int c = q * 256 + tid;
      const int r = c >> 3;
      const int js = (c & 7) ^ (r & 7);
      const unsigned short* gf = fbase + r * D + kt * BK + js * 8;
      const unsigned short* ga = abase + r * D + kt * BK + js * 8;
      gload_lds16(gf, &Fs[c * 8]);
      gload_lds16(ga, &As[c * 8]);
    }
    __syncthreads();  // vmcnt drained by compiler before barrier
#pragma unroll
    for (int h = 0; h < 2; ++h) {  // two K=32 halves of BK=64
      bf16x8 afr[2], bfr[8];
      const int j = h * 4 + half;  // 16B slot within the 8-slot row
#pragma unroll
      for (int m = 0; m < 2; ++m) {
        const int row = wv * 32 + m * 16 + l15;
        afr[m] = *reinterpret_cast<const bf16x8*>(&Fs[(row * 8 + (j ^ (row & 7))) * 8]);
      }
#pragma unroll
      for (int n = 0; n < 8; ++n) {
        const int row = n * 16 + l15;
        bfr[n] = *reinterpret_cast<const bf16x8*>(&As[(row * 8 + (j ^ (row & 7))) * 8]);
      }
#pragma unroll
      for (int m = 0; m < 2; ++m)
#pragma unroll
        for (int n = 0; n < 8; ++n)
          acc[m][n] = __builtin_amdgcn_mfma_f32_16x16x32_bf16(afr[m], bfr[n],
                                                              acc[m][n], 0, 0, 0);
    }
  }

  // Epilogue: per-row sum of exp(logit) over the 128 cols of this tile.
  // C/D layout: col = bcol*128 + n*16 + l15, row = wv*32 + m*16 + half*4 + e.
#pragma unroll
  for (int m = 0; m < 2; ++m) {
#pragma unroll
    for (int e = 0; e < 4; ++e) {
      float s = 0.0f;
#pragma unroll
      for (int n = 0; n < 8; ++n) s += __expf(fast_logit(acc[m][n][e]));
#pragma unroll
      for (int msk = 1; msk <= 8; msk <<= 1) s += __shfl_xor(s, msk, 64);
      if (l15 == 0) {
        const int row = brow * BM + wv * 32 + m * 16 + half * 4 + e;
        partials[(size_t)row * ncb + bcol] = s;
      }
    }
  }
}

// --- combine per-row partials: term_i = log(S_i) - logit_ii; block partial sums ---
__global__ __launch_bounds__(256) void combine_rows(
    const float* __restrict__ partials, const unsigned short* __restrict__ fnb,
    const unsigned short* __restrict__ anb, float* __restrict__ blocksums,
    int N, int ncb) {
  __shared__ float red[4];
  const int i = blockIdx.x * blockDim.x + threadIdx.x;
  float S = 0.0f;
  const float4* pp = reinterpret_cast<const float4*>(partials + (size_t)i * ncb);
#pragma unroll 4
  for (int cb = 0; cb < ncb / 4; ++cb) {
    const float4 p = pp[cb];
    S += (p.x + p.y) + (p.z + p.w);
  }
  // diagonal logit: dot(f_i, a_i) from the same bf16 data the MFMA consumed
  const uint4* fp = reinterpret_cast<const uint4*>(fnb + (size_t)i * D);
  const uint4* ap = reinterpret_cast<const uint4*>(anb + (size_t)i * D);
  float dot = 0.0f;
#pragma unroll 4
  for (int q = 0; q < D / 8; ++q) {
    const uint4 f = fp[q], a = ap[q];
    const unsigned int fw[4] = {f.x, f.y, f.z, f.w};
    const unsigned int aw[4] = {a.x, a.y, a.z, a.w};
#pragma unroll
    for (int w = 0; w < 4; ++w) {
      dot += __uint_as_float(fw[w] << 16) * __uint_as_float(aw[w] << 16);
      dot += __uint_as_float(fw[w] & 0xFFFF0000u) * __uint_as_float(aw[w] & 0xFFFF0000u);
    }
  }
  float t = __logf(S) - fast_logit(dot);
  // block-level reduction of terms
#pragma unroll
  for (int m = 32; m >= 1; m >>= 1) t += __shfl_xor(t, m, 64);
  const int wave = threadIdx.x >> 6;
  if ((threadIdx.x & 63) == 0) red[wave] = t;
  __syncthreads();
  if (threadIdx.x == 0)
    blocksums[blockIdx.x] = (red[0] + red[1]) + (red[2] + red[3]);
}

// --- deterministic final reduction over nb block sums ---
__global__ __launch_bounds__(64) void reduce_terms(const float* __restrict__ blocksums,
                                                   float* __restrict__ out, int nb, int N) {
  float s = 0.0f;
  for (int i = threadIdx.x; i < nb; i += 64) s += blocksums[i];
#pragma unroll
  for (int m = 32; m >= 1; m >>= 1) s += __shfl_xor(s, m, 64);
  if (threadIdx.x == 0) out[0] = s / (float)N;
}

}  // namespace

extern "C" void kernel_launch(void* const* d_in, const int* in_sizes, int n_in,
                              void* d_out, int out_size, void* d_ws, size_t ws_size,
                              hipStream_t stream) {
  const float* face = (const float*)d_in[0];
  const float* audio = (const float*)d_in[1];
  const int N = in_sizes[0] / D;  // 8192
  const int ncb = N / BN;         // 64
  const int nb = N / 256;         // combine blocks

  // workspace: fnb[N*D] bf16 | anb[N*D] bf16 | partials[N*ncb] f32 | blocksums[nb] f32
  unsigned short* fnb = (unsigned short*)d_ws;
  unsigned short* anb = fnb + (size_t)N * D;
  float* partials = (float*)(anb + (size_t)N * D);
  float* blocksums = partials + (size_t)N * ncb;

  normalize_rows_bf<<<N / 4, 256, 0, stream>>>(face, fnb);
  normalize_rows_bf<<<N / 4, 256, 0, stream>>>(audio, anb);
  dim3 grid(N / BM, N / BN);
  tile_partial_lse<<<grid, 256, 0, stream>>>(fnb, anb, partials, N, ncb);
  combine_rows<<<nb, 256, 0, stream>>>(partials, fnb, anb, blocksums, N, ncb);
  reduce_terms<<<1, 64, 0, stream>>>(blocksums, (float*)d_out, nb, N);
}